// Round 3
// baseline (710.648 us; speedup 1.0000x reference)
//
#include <hip/hip_runtime.h>
#include <hip/hip_bf16.h>

// Problem constants
#define T_TOK 4096
#define DDIM  2048
#define IDIM  1024
#define NEXP  8
#define NPAIR 8192    // T_TOK * top_k
#define TPAIR 12288   // NPAIR + T_TOK shared rows

typedef unsigned short u16;
typedef __bf16 bf16x8 __attribute__((ext_vector_type(8)));
typedef float  f32x4  __attribute__((ext_vector_type(4)));
typedef unsigned short u16x4 __attribute__((ext_vector_type(4)));
typedef unsigned short u16x8 __attribute__((ext_vector_type(8)));

__device__ __forceinline__ u16 f2bf(float f) {
  union { float f; unsigned u; } v; v.f = f;
  unsigned r = v.u + 0x7fffu + ((v.u >> 16) & 1u);   // RNE
  return (u16)(r >> 16);
}

// async global->LDS, 16B per lane; LDS dest is wave-uniform base (+lane*16 by HW)
__device__ __forceinline__ void gll16(const void* g, void* l) {
  __builtin_amdgcn_global_load_lds(
      (__attribute__((address_space(1))) void*)(g),
      (__attribute__((address_space(3))) void*)(l),
      16, 0, 0);
}

#define MFMA16(a, b, c) __builtin_amdgcn_mfma_f32_16x16x32_bf16((a), (b), (c), 0, 0, 0)

// ---------------- router: logits = x @ rw (fp64 accum), top-2, sigmoid ----------------
__global__ __launch_bounds__(256)
void router_kernel(const float* __restrict__ x, const float* __restrict__ rw,
                   int* __restrict__ top_idx, float* __restrict__ top_w,
                   int* __restrict__ counts) {
  int t = blockIdx.x;
  int tid = threadIdx.x;
  int lane = tid & 63, wave = tid >> 6;
  const float* xr = x + (size_t)t * DDIM;
  double acc[NEXP];
#pragma unroll
  for (int e = 0; e < NEXP; ++e) acc[e] = 0.0;
  for (int d = tid; d < DDIM; d += 256) {
    double xv = (double)xr[d];
    const float* r = rw + (size_t)d * NEXP;
#pragma unroll
    for (int e = 0; e < NEXP; ++e) acc[e] += xv * (double)r[e];
  }
  __shared__ double wred[4][NEXP];
#pragma unroll
  for (int e = 0; e < NEXP; ++e) {
    double v = acc[e];
    for (int s = 32; s > 0; s >>= 1) v += __shfl_down(v, s);
    if (lane == 0) wred[wave][e] = v;
  }
  __syncthreads();
  if (tid == 0) {
    float lg[NEXP];
#pragma unroll
    for (int e = 0; e < NEXP; ++e)
      lg[e] = (float)(wred[0][e] + wred[1][e] + wred[2][e] + wred[3][e]);
    int e0 = 0; float v0 = lg[0];
    for (int e = 1; e < NEXP; ++e) if (lg[e] > v0) { v0 = lg[e]; e0 = e; }
    int e1 = -1; float v1 = -3.4e38f;
    for (int e = 0; e < NEXP; ++e) if (e != e0 && lg[e] > v1) { v1 = lg[e]; e1 = e; }
    float p0 = 1.0f / (1.0f + __expf(-v0));
    float p1 = 1.0f / (1.0f + __expf(-v1));
    top_idx[t * 2 + 0] = e0; top_idx[t * 2 + 1] = e1;
    top_w[t * 2 + 0] = p0;  top_w[t * 2 + 1] = p1;
    atomicAdd(&counts[e0], 1);
    atomicAdd(&counts[e1], 1);
  }
}

__global__ void init_kernel(int* counts) {
  if (threadIdx.x < NEXP) counts[threadIdx.x] = 0;
}

// prefix sum over 8 routed experts + shared (e=8); 256-row tile table
__global__ void offsets_kernel(const int* __restrict__ counts, int* __restrict__ offs,
                               int* __restrict__ fill, int* __restrict__ tab,
                               int* __restrict__ ntl) {
  if (blockIdx.x == 0 && threadIdx.x == 0) {
    int off = 0, nt = 0;
    for (int e = 0; e < NEXP; ++e) {
      offs[e] = off;
      int c = counts[e];
      int tb = (c + 255) >> 8;
      for (int t = 0; t < tb; ++t) tab[nt++] = (e << 16) | t;
      off += c;
      fill[e] = 0;
    }
    offs[NEXP] = NPAIR;       // routed total is exactly NPAIR
    offs[NEXP + 1] = TPAIR;   // shared region
    for (int t = 0; t < 16; ++t) tab[nt++] = (NEXP << 16) | t;  // 4096/256 shared tiles
    *ntl = nt;
    for (int i = nt; i < 144; ++i) tab[i] = 0;
  }
}

__global__ __launch_bounds__(256)
void scatter_kernel(const int* __restrict__ top_idx, const float* __restrict__ top_w,
                    const int* __restrict__ offs, int* __restrict__ fill,
                    int* __restrict__ tlist, float* __restrict__ pw,
                    int* __restrict__ pos_of) {
  int t = blockIdx.x * blockDim.x + threadIdx.x;
  if (t >= T_TOK) return;
#pragma unroll
  for (int k = 0; k < 2; ++k) {
    int e = top_idx[t * 2 + k];
    float w = top_w[t * 2 + k];
    int pos = offs[e] + atomicAdd(&fill[e], 1);
    tlist[pos] = t;
    pw[pos] = w;
    pos_of[t * 2 + k] = pos;
  }
  tlist[NPAIR + t] = t;   // shared region: identity gather, weight 1
  pw[NPAIR + t] = 1.0f;
}

// ---------------- fp32 -> bf16 convert of x ----------------
__global__ __launch_bounds__(256)
void cvt_x_kernel(const float* __restrict__ in, u16* __restrict__ out) {
  size_t i = ((size_t)blockIdx.x * blockDim.x + threadIdx.x) * 4;
  float4 v = *(const float4*)(in + i);
  u16x4 o;
  o.x = f2bf(v.x); o.y = f2bf(v.y); o.z = f2bf(v.z); o.w = f2bf(v.w);
  *(u16x4*)(out + i) = o;
}

// ---------------- 64x64 fp32->bf16 transpose core ----------------
__device__ __forceinline__ void t64_core(const float* __restrict__ inb, int inRS,
                                         u16* __restrict__ outb, int outRS2) {
  __shared__ float tile[64][65];
  int tid = threadIdx.x;
  int tx = tid & 15, ty = tid >> 4;
#pragma unroll
  for (int rr = 0; rr < 4; ++rr) {
    int r = ty + rr * 16;
    float4 v = *(const float4*)(inb + (size_t)r * inRS + tx * 4);
    tile[r][tx * 4 + 0] = v.x; tile[r][tx * 4 + 1] = v.y;
    tile[r][tx * 4 + 2] = v.z; tile[r][tx * 4 + 3] = v.w;
  }
  __syncthreads();
  int n = tid >> 2, c8 = tid & 3;
#pragma unroll
  for (int cc = 0; cc < 2; ++cc) {
    int k0 = (c8 + cc * 4) * 8;
    u16x8 o;
#pragma unroll
    for (int j = 0; j < 8; ++j) o[j] = f2bf(tile[k0 + j][n]);
    *(u16x8*)(outb + (size_t)n * outRS2 + k0) = o;
  }
}

// gate_up_w [E][D][2I] -> gut slab e: [2I][D], rows interleaved 2i+s
__global__ __launch_bounds__(256)
void t_gu_kernel(const float* __restrict__ in, u16* __restrict__ out) {
  int z = blockIdx.z, e = z >> 1, s = z & 1;
  int kt = blockIdx.x, nt = blockIdx.y;
  const float* inb = in + (size_t)e * DDIM * (2 * IDIM) + (size_t)(kt * 64) * (2 * IDIM)
                        + (size_t)s * IDIM + nt * 64;
  u16* outb = out + (size_t)e * (2 * IDIM) * DDIM + (size_t)(2 * (nt * 64) + s) * DDIM + kt * 64;
  t64_core(inb, 2 * IDIM, outb, 2 * DDIM);
}
// shared gate/up [D][I] -> gut slab 8, interleaved
__global__ __launch_bounds__(256)
void t_sgu_kernel(const float* __restrict__ sg, const float* __restrict__ su,
                  u16* __restrict__ out) {
  int s = blockIdx.z;
  const float* in = s ? su : sg;
  int kt = blockIdx.x, nt = blockIdx.y;
  const float* inb = in + (size_t)(kt * 64) * IDIM + nt * 64;
  u16* outb = out + (size_t)NEXP * (2 * IDIM) * DDIM + (size_t)(2 * (nt * 64) + s) * DDIM + kt * 64;
  t64_core(inb, IDIM, outb, 2 * DDIM);
}
// down_w [E][I][D] -> dwt slab e: [D][I]
__global__ __launch_bounds__(256)
void t_dw_kernel(const float* __restrict__ in, u16* __restrict__ out) {
  int e = blockIdx.z;
  int kt = blockIdx.x, nt = blockIdx.y;
  const float* inb = in + (size_t)e * IDIM * DDIM + (size_t)(kt * 64) * DDIM + nt * 64;
  u16* outb = out + (size_t)e * DDIM * IDIM + (size_t)(nt * 64) * IDIM + kt * 64;
  t64_core(inb, DDIM, outb, IDIM);
}
// shared_down [I][D] -> dwt slab 8
__global__ __launch_bounds__(256)
void t_sd_kernel(const float* __restrict__ in, u16* __restrict__ out) {
  int kt = blockIdx.x, nt = blockIdx.y;
  const float* inb = in + (size_t)(kt * 64) * DDIM + nt * 64;
  u16* outb = out + (size_t)NEXP * DDIM * IDIM + (size_t)(nt * 64) * IDIM + kt * 64;
  t64_core(inb, DDIM, outb, IDIM);
}

// ---------------- 256x256 deep-pipelined GEMM ----------------
// BM=BN=256, BK=64, 8 waves (2Mx4N), LDS 128KiB dbuf, 4 phases per K-tile.
// v2 schedule: stage chunks issued ONE PHASE EARLIER than v1 (5-phase issue->wait
// distance, 8-10 loads in flight, waits vmcnt(6), never 0 in the loop):
//   S1(t+1)@P0(t), S2(t+1)@P1(t), S3(t+1)@P2(t), S0(t+2)@P3(t)
// S0(t+2) writes the CURRENT buffer: safe because all LDS reads of tile t finish
// by P2(t) and P3 opens with a barrier. Manual 2x unroll makes buffer parity
// compile-time (ds_read offsets fold to immediates).
// Wait accounting (steady state, 10 in flight at P0):
//   P0 needs S0(t)+S1(t) = oldest 4  -> vmcnt(6)
//   P1 needs S2(t)       = oldest 2 of 8 -> vmcnt(6)
//   P2 needs S3(t)       = oldest 2 of 8 -> vmcnt(6)
// LDS swizzle (T2, both sides): slot s of row r holds global k-chunk s^(r&7).
template <bool GATEUP, int KD>
__global__ __launch_bounds__(512)
void gemm8_kernel(const u16* __restrict__ A, const u16* __restrict__ Bt,
                  float* __restrict__ outp, u16* __restrict__ hout,
                  const int* __restrict__ tab, const int* __restrict__ ntl,
                  const int* __restrict__ offs, const int* __restrict__ tlist,
                  const float* __restrict__ pw) {
  constexpr int BK = 64;
  constexpr int NKT = KD / BK;   // 32 (gateup) / 16 (down), always even
  // 128 KiB: A dbuf = sm[0..16384), sm[16384..32768); B dbuf = +32768, +49152 (u16 units)
  __shared__ alignas(16) u16 sm[65536];

  int bid = blockIdx.x;
  int bx = bid >> 3;        // M-tile index (slow)
  int by = bid & 7;         // N column (fast; same-col blocks share B slab in L2)
  int nt = *ntl;
  if (bx >= nt) return;
  int tt = tab[bx];
  int e = tt >> 16, rb = tt & 0xffff;
  int seg = offs[e];
  int mcnt = offs[e + 1] - seg;
  int m0 = rb * 256, n0 = by * 256;
  const u16* Bte = Bt + (size_t)e * 2048 * KD + (size_t)n0 * KD;

  int tid = threadIdx.x;
  int lane = tid & 63, w = tid >> 6;
  int wr = w >> 2, wc = w & 3;           // wave grid 2(M) x 4(N), wave owns 128x64 out

  // ---- staging setup ----
  int wq = w & 3;                        // A staging: rows wr*128 + h*64 + wq*16 + [0,16)
  int wch = w >> 1, wo = w & 1;          // B staging: rows wch*64 + wo*16 + s*32 + [0,16)
  int srow = lane >> 3;                  // 0..7 : row within 8-row call
  int swz = (lane & 7) ^ srow;           // pre-swizzled k-chunk to fetch (involution)

  const u16* pA[2][2];                   // [half(mh)][call j]
#pragma unroll
  for (int h = 0; h < 2; ++h)
#pragma unroll
    for (int j = 0; j < 2; ++j) {
      int gl = wr * 128 + h * 64 + wq * 16 + j * 8 + srow;   // local row in tile
      int g = m0 + gl;
      if (g > mcnt - 1) g = mcnt - 1;                        // clamp within segment
      size_t row = GATEUP ? (size_t)tlist[seg + g] : (size_t)(seg + g);
      pA[h][j] = A + row * KD + swz * 8;
    }
  const u16* pB = Bte + (size_t)(wch * 64 + wo * 16 + srow) * KD + swz * 8;

  auto stA = [&](int h, int kn, u16* dst) {
    u16* d = dst + wr * 8192 + wq * 1024 + h * 4096;
    gll16(pA[h][0] + kn, d);
    gll16(pA[h][1] + kn, d + 512);
  };
  auto stB = [&](int s, int kn, u16* dst) {
    u16* d = dst + wch * 4096 + wo * 1024 + s * 2048;
    gll16(pB + (size_t)(s * 32) * KD + kn, d);
    gll16(pB + (size_t)(s * 32 + 8) * KD + kn, d + 512);
  };

  // ---- read-side fragment offsets (u16 units, includes XOR swizzle) ----
  int rlo = lane & 15, g4 = lane >> 4;
  int aoff0 = rlo * 64 + ((g4 ^ (rlo & 7)) * 8);          // ks=0 (k-chunks 0..3)
  int aoff1 = rlo * 64 + (((4 + g4) ^ (rlo & 7)) * 8);    // ks=1 (k-chunks 4..7)

  bf16x8 a0[4][2], a1[4][2], b0[2][2], b1[2][2];
  f32x4 acc[8][4] = {};

  // prologue: S0(0),S1(0),S2(0),S3(0) -> buf0 ; S0(1) -> buf1  (10 loads in flight)
  stA(0, 0, sm);
  stB(0, 0, sm + 32768);
  stB(1, 0, sm + 32768);
  stA(1, 0, sm);
  stA(0, BK, sm + 16384);

  for (int tp = 0; tp < NKT; tp += 2) {
#pragma unroll
    for (int u = 0; u < 2; ++u) {
      const int t = tp + u;
      const int AB = u * 16384;              // compile-time buffer parity
      const u16* Ar = sm + AB + wr * 8192;
      const u16* Br = sm + 32768 + AB + wc * 4096;
      u16* An = sm + (AB ^ 16384);
      u16* Bn = sm + 32768 + (AB ^ 16384);
      u16* Ac = sm + AB;
      int kn1 = (t + 1 < NKT) ? (t + 1) * BK : 0;  // stages for tile t+1 (dummy ok)
      int kn2 = (t + 2 < NKT) ? (t + 2) * BK : 0;  // stage S0 for tile t+2 (dummy ok)

      // ---- P0: read A-mh0 + B-nh0 | stage S1(t+1) | MFMA Q3(t-1) ----
      asm volatile("s_waitcnt vmcnt(6)" ::: "memory");
      __builtin_amdgcn_s_barrier();
#pragma unroll
      for (int i = 0; i < 4; ++i) {
        a0[i][0] = *(const bf16x8*)(Ar + i * 1024 + aoff0);
        a0[i][1] = *(const bf16x8*)(Ar + i * 1024 + aoff1);
      }
#pragma unroll
      for (int j = 0; j < 2; ++j) {
        b0[j][0] = *(const bf16x8*)(Br + j * 1024 + aoff0);
        b0[j][1] = *(const bf16x8*)(Br + j * 1024 + aoff1);
      }
      stB(0, kn1, Bn);
      if (t) {
        __builtin_amdgcn_s_setprio(1);
#pragma unroll
        for (int i = 0; i < 4; ++i)
#pragma unroll
          for (int j = 0; j < 2; ++j) {
            acc[4 + i][2 + j] = MFMA16(a1[i][0], b1[j][0], acc[4 + i][2 + j]);
            acc[4 + i][2 + j] = MFMA16(a1[i][1], b1[j][1], acc[4 + i][2 + j]);
          }
        __builtin_amdgcn_s_setprio(0);
      }

      // ---- P1: read B-nh1 | stage S2(t+1) | MFMA Q0 ----
      asm volatile("s_waitcnt vmcnt(6)" ::: "memory");
      __builtin_amdgcn_s_barrier();
#pragma unroll
      for (int j = 0; j < 2; ++j) {
        b1[j][0] = *(const bf16x8*)(Br + 2048 + j * 1024 + aoff0);
        b1[j][1] = *(const bf16x8*)(Br + 2048 + j * 1024 + aoff1);
      }
      stB(1, kn1, Bn);
      __builtin_amdgcn_s_setprio(1);
#pragma unroll
      for (int i = 0; i < 4; ++i)
#pragma unroll
        for (int j = 0; j < 2; ++j) {
          acc[i][j] = MFMA16(a0[i][0], b0[j][0], acc[i][j]);
          acc[i][j] = MFMA16(a0[i][1], b0[j][1], acc[i][j]);
        }
      __builtin_amdgcn_s_setprio(0);

      // ---- P2: read A-mh1 | stage S3(t+1) | MFMA Q1 ----
      asm volatile("s_waitcnt vmcnt(6)" ::: "memory");
      __builtin_amdgcn_s_barrier();
#pragma unroll
      for (int i = 0; i < 4; ++i) {
        a1[i][0] = *(const bf16x8*)(Ar + 4096 + i * 1024 + aoff0);
        a1[i][1] = *(const bf16x8*)(Ar + 4096 + i * 1024 + aoff1);
      }
      stA(1, kn1, An);
      __builtin_amdgcn_s_setprio(1);
#pragma unroll
      for (int i = 0; i < 4; ++i)
#pragma unroll
        for (int j = 0; j < 2; ++j) {
          acc[i][2 + j] = MFMA16(a0[i][0], b1[j][0], acc[i][2 + j]);
          acc[i][2 + j] = MFMA16(a0[i][1], b1[j][1], acc[i][2 + j]);
        }
      __builtin_amdgcn_s_setprio(0);

      // ---- P3: stage S0(t+2) into CURRENT buffer | MFMA Q2 (no wait) ----
      __builtin_amdgcn_s_barrier();
      stA(0, kn2, Ac);
      __builtin_amdgcn_s_setprio(1);
#pragma unroll
      for (int i = 0; i < 4; ++i)
#pragma unroll
        for (int j = 0; j < 2; ++j) {
          acc[4 + i][j] = MFMA16(a1[i][0], b0[j][0], acc[4 + i][j]);
          acc[4 + i][j] = MFMA16(a1[i][1], b0[j][1], acc[4 + i][j]);
        }
      __builtin_amdgcn_s_setprio(0);
    }
  }
  // final Q3 of last tile
#pragma unroll
  for (int i = 0; i < 4; ++i)
#pragma unroll
    for (int j = 0; j < 2; ++j) {
      acc[4 + i][2 + j] = MFMA16(a1[i][0], b1[j][0], acc[4 + i][2 + j]);
      acc[4 + i][2 + j] = MFMA16(a1[i][1], b1[j][1], acc[4 + i][2 + j]);
    }

  // ---- epilogue: C/D layout col = lane&15 (N), row = (lane>>4)*4 + r (M) ----
  int cn = lane & 15;
  int rq = (lane >> 4) * 4;

  if constexpr (GATEUP) {
#pragma unroll
    for (int mf = 0; mf < 8; ++mf) {
#pragma unroll
      for (int r = 0; r < 4; ++r) {
        int mloc = wr * 128 + mf * 16 + rq + r;
        int mg = m0 + mloc;
        bool valid = (mg < mcnt);
        float p = valid ? pw[seg + mg] : 0.0f;
#pragma unroll
        for (int nf = 0; nf < 4; ++nf) {
          float v = acc[mf][nf][r] * p;       // p applied PRE-silu (matches reference)
          float o = __shfl_xor(v, 1);         // partner column (gate<->up)
          if (!(cn & 1) && valid) {
            float g = v, u2 = o;
            float h = (g / (1.0f + __expf(-g))) * u2;   // silu(g)*u
            int ncol = n0 + wc * 64 + nf * 16 + cn;
            hout[(size_t)(seg + mg) * IDIM + (ncol >> 1)] = f2bf(h);
          }
        }
      }
    }
  } else {
#pragma unroll
    for (int mf = 0; mf < 8; ++mf) {
#pragma unroll
      for (int r = 0; r < 4; ++r) {
        int mloc = wr * 128 + mf * 16 + rq + r;
        int mg = m0 + mloc;
        if (mg < mcnt) {
#pragma unroll
          for (int nf = 0; nf < 4; ++nf) {
            int ncol = n0 + wc * 64 + nf * 16 + cn;
            outp[(size_t)(seg + mg) * DDIM + ncol] = acc[mf][nf][r];
          }
        }
      }
    }
  }
}

// ---------------- final combine: out[t] = dout[p0] + dout[p1] + dout[shared_t] ----------------
__global__ __launch_bounds__(256)
void combine_kernel(const float* __restrict__ dout, const int* __restrict__ pos_of,
                    float* __restrict__ out) {
  int idx = blockIdx.x * 256 + threadIdx.x;
  int t = idx >> 9;              // 512 float4 per row
  int c = (idx & 511) * 4;
  int p0 = pos_of[t * 2];
  int p1 = pos_of[t * 2 + 1];
  float4 a = *(const float4*)(dout + (size_t)p0 * DDIM + c);
  float4 b = *(const float4*)(dout + (size_t)p1 * DDIM + c);
  float4 s = *(const float4*)(dout + (size_t)(NPAIR + t) * DDIM + c);
  float4 o;
  o.x = a.x + b.x + s.x; o.y = a.y + b.y + s.y;
  o.z = a.z + b.z + s.z; o.w = a.w + b.w + s.w;
  *(float4*)(out + (size_t)t * DDIM + c) = o;
}

// ---------------- launch ----------------
extern "C" void kernel_launch(void* const* d_in, const int* in_sizes, int n_in,
                              void* d_out, int out_size, void* d_ws, size_t ws_size,
                              hipStream_t stream) {
  const float* x   = (const float*)d_in[0];
  const float* rw  = (const float*)d_in[1];
  const float* guw = (const float*)d_in[2];
  const float* dw  = (const float*)d_in[3];
  const float* sgw = (const float*)d_in[4];
  const float* suw = (const float*)d_in[5];
  const float* sdw = (const float*)d_in[6];
  float* outp = (float*)d_out;
  (void)in_sizes; (void)n_in; (void)out_size; (void)ws_size;

  char* ws = (char*)d_ws;
  size_t off = 0;
  auto alloc = [&](size_t bytes) -> void* {
    void* p = ws + off;
    off += (bytes + 255) & ~(size_t)255;
    return p;
  };
  // region0: gut (75.5 MB) + xb (16.8 MB) during gateup; overlaid by dout (100.7 MB) for down
  const size_t gut_b  = (size_t)(NEXP + 1) * 2 * IDIM * DDIM * 2;   // 75.5 MB
  const size_t xb_b   = (size_t)T_TOK * DDIM * 2;                   // 16.8 MB
  const size_t dout_b = (size_t)TPAIR * DDIM * 4;                   // 100.7 MB
  char* region0 = (char*)alloc(dout_b > gut_b + xb_b ? dout_b : gut_b + xb_b);
  u16*   gut  = (u16*)region0;
  u16*   xb   = (u16*)(region0 + gut_b);
  float* dout = (float*)region0;

  u16* dwt = (u16*)alloc((size_t)(NEXP + 1) * DDIM * IDIM * 2);     // 37.75 MB
  u16* he  = (u16*)alloc((size_t)TPAIR * IDIM * 2);                 // 25.2 MB
  int* top_idx = (int*)alloc(T_TOK * 2 * 4);
  float* top_w = (float*)alloc(T_TOK * 2 * 4);
  int* counts  = (int*)alloc(NEXP * 4);
  int* offs    = (int*)alloc((NEXP + 2) * 4);
  int* fill    = (int*)alloc(NEXP * 4);
  int* tab     = (int*)alloc(144 * 4);
  int* ntl     = (int*)alloc(4);
  int* tlist   = (int*)alloc(TPAIR * 4);
  float* pw    = (float*)alloc(TPAIR * 4);
  int* pos_of  = (int*)alloc(NPAIR * 4);

  // routing
  init_kernel<<<dim3(1), dim3(64), 0, stream>>>(counts);
  router_kernel<<<dim3(T_TOK), dim3(256), 0, stream>>>(x, rw, top_idx, top_w, counts);
  offsets_kernel<<<dim3(1), dim3(1), 0, stream>>>(counts, offs, fill, tab, ntl);
  scatter_kernel<<<dim3(16), dim3(256), 0, stream>>>(top_idx, top_w, offs, fill, tlist, pw, pos_of);

  // fp32 -> bf16 (+transpose) pre-pass
  cvt_x_kernel<<<dim3(8192), dim3(256), 0, stream>>>(x, xb);
  t_gu_kernel<<<dim3(32, 16, 16), dim3(256), 0, stream>>>(guw, gut);
  t_sgu_kernel<<<dim3(32, 16, 2), dim3(256), 0, stream>>>(sgw, suw, gut);
  t_dw_kernel<<<dim3(16, 32, 8), dim3(256), 0, stream>>>(dw, dwt);
  t_sd_kernel<<<dim3(16, 32, 1), dim3(256), 0, stream>>>(sdw, dwt);

  // gateup over all 12288 pairs (routed + shared): he = silu(p*(x@Wg)) * (p*(x@Wu))
  gemm8_kernel<true, DDIM><<<dim3(56 * 8), dim3(512), 0, stream>>>(
      xb, gut, nullptr, he, tab, ntl, offs, tlist, pw);
  // down over all pairs: dout[pair] = he[pair] @ Wd   (overlays gut/xb — both dead now)
  gemm8_kernel<false, IDIM><<<dim3(56 * 8), dim3(512), 0, stream>>>(
      he, dwt, dout, nullptr, tab, ntl, offs, tlist, pw);

  // out[t] = dout[p0] + dout[p1] + dout[8192+t]
  combine_kernel<<<dim3(8192), dim3(256), 0, stream>>>(dout, pos_of, outp);
}

// Round 5
// 655.178 us; speedup vs baseline: 1.0847x; 1.0847x over previous
//
#include <hip/hip_runtime.h>
#include <hip/hip_bf16.h>

// Problem constants
#define T_TOK 4096
#define DDIM  2048
#define IDIM  1024
#define NEXP  8
#define NPAIR 8192    // T_TOK * top_k
#define TPAIR 12288   // NPAIR + T_TOK shared rows

typedef unsigned short u16;
typedef __bf16 bf16x8 __attribute__((ext_vector_type(8)));
typedef float  f32x4  __attribute__((ext_vector_type(4)));
typedef unsigned short u16x4 __attribute__((ext_vector_type(4)));
typedef unsigned short u16x8 __attribute__((ext_vector_type(8)));

__device__ __forceinline__ u16 f2bf(float f) {
  union { float f; unsigned u; } v; v.f = f;
  unsigned r = v.u + 0x7fffu + ((v.u >> 16) & 1u);   // RNE
  return (u16)(r >> 16);
}

// async global->LDS, 16B per lane; LDS dest is wave-uniform base (+lane*16 by HW)
__device__ __forceinline__ void gll16(const void* g, void* l) {
  __builtin_amdgcn_global_load_lds(
      (__attribute__((address_space(1))) void*)(g),
      (__attribute__((address_space(3))) void*)(l),
      16, 0, 0);
}

#define MFMA16(a, b, c) __builtin_amdgcn_mfma_f32_16x16x32_bf16((a), (b), (c), 0, 0, 0)

// ---------------- router: logits = x @ rw (fp64 accum), top-2, sigmoid ----------------
// Fused: also emits the bf16 copy of x (kills the separate cvt_x kernel + launch bubble).
__global__ __launch_bounds__(256)
void router_kernel(const float* __restrict__ x, const float* __restrict__ rw,
                   int* __restrict__ top_idx, float* __restrict__ top_w,
                   int* __restrict__ counts, u16* __restrict__ xb) {
  int t = blockIdx.x;
  int tid = threadIdx.x;
  int lane = tid & 63, wave = tid >> 6;
  const float* xr = x + (size_t)t * DDIM;

  // bf16 conversion of this token's row (coalesced, 8 elems/thread)
  {
    int d0 = tid * 8;
    float4 v0 = *(const float4*)(xr + d0);
    float4 v1 = *(const float4*)(xr + d0 + 4);
    u16x8 o;
    o[0] = f2bf(v0.x); o[1] = f2bf(v0.y); o[2] = f2bf(v0.z); o[3] = f2bf(v0.w);
    o[4] = f2bf(v1.x); o[5] = f2bf(v1.y); o[6] = f2bf(v1.z); o[7] = f2bf(v1.w);
    *(u16x8*)(xb + (size_t)t * DDIM + d0) = o;
  }

  double acc[NEXP];
#pragma unroll
  for (int e = 0; e < NEXP; ++e) acc[e] = 0.0;
  for (int d = tid; d < DDIM; d += 256) {
    double xv = (double)xr[d];
    const float* r = rw + (size_t)d * NEXP;
#pragma unroll
    for (int e = 0; e < NEXP; ++e) acc[e] += xv * (double)r[e];
  }
  __shared__ double wred[4][NEXP];
#pragma unroll
  for (int e = 0; e < NEXP; ++e) {
    double v = acc[e];
    for (int s = 32; s > 0; s >>= 1) v += __shfl_down(v, s);
    if (lane == 0) wred[wave][e] = v;
  }
  __syncthreads();
  if (tid == 0) {
    float lg[NEXP];
#pragma unroll
    for (int e = 0; e < NEXP; ++e)
      lg[e] = (float)(wred[0][e] + wred[1][e] + wred[2][e] + wred[3][e]);
    int e0 = 0; float v0 = lg[0];
    for (int e = 1; e < NEXP; ++e) if (lg[e] > v0) { v0 = lg[e]; e0 = e; }
    int e1 = -1; float v1 = -3.4e38f;
    for (int e = 0; e < NEXP; ++e) if (e != e0 && lg[e] > v1) { v1 = lg[e]; e1 = e; }
    float p0 = 1.0f / (1.0f + __expf(-v0));
    float p1 = 1.0f / (1.0f + __expf(-v1));
    top_idx[t * 2 + 0] = e0; top_idx[t * 2 + 1] = e1;
    top_w[t * 2 + 0] = p0;  top_w[t * 2 + 1] = p1;
    atomicAdd(&counts[e0], 1);
    atomicAdd(&counts[e1], 1);
  }
}

__global__ void init_kernel(int* counts) {
  if (threadIdx.x < NEXP) counts[threadIdx.x] = 0;
}

// prefix sum over 8 routed experts + shared (e=8); 256-row tile table
__global__ void offsets_kernel(const int* __restrict__ counts, int* __restrict__ offs,
                               int* __restrict__ fill, int* __restrict__ tab,
                               int* __restrict__ ntl) {
  if (blockIdx.x == 0 && threadIdx.x == 0) {
    int off = 0, nt = 0;
    for (int e = 0; e < NEXP; ++e) {
      offs[e] = off;
      int c = counts[e];
      int tb = (c + 255) >> 8;
      for (int t = 0; t < tb; ++t) tab[nt++] = (e << 16) | t;
      off += c;
      fill[e] = 0;
    }
    offs[NEXP] = NPAIR;       // routed total is exactly NPAIR
    offs[NEXP + 1] = TPAIR;   // shared region
    for (int t = 0; t < 16; ++t) tab[nt++] = (NEXP << 16) | t;  // 4096/256 shared tiles
    *ntl = nt;
    for (int i = nt; i < 144; ++i) tab[i] = 0;
  }
}

__global__ __launch_bounds__(256)
void scatter_kernel(const int* __restrict__ top_idx, const float* __restrict__ top_w,
                    const int* __restrict__ offs, int* __restrict__ fill,
                    int* __restrict__ tlist, float* __restrict__ pw,
                    int* __restrict__ pos_of) {
  int t = blockIdx.x * blockDim.x + threadIdx.x;
  if (t >= T_TOK) return;
#pragma unroll
  for (int k = 0; k < 2; ++k) {
    int e = top_idx[t * 2 + k];
    float w = top_w[t * 2 + k];
    int pos = offs[e] + atomicAdd(&fill[e], 1);
    tlist[pos] = t;
    pw[pos] = w;
    pos_of[t * 2 + k] = pos;
  }
  tlist[NPAIR + t] = t;   // shared region: identity gather, weight 1
  pw[NPAIR + t] = 1.0f;
}

// ---------------- 64x64 fp32->bf16 transpose core ----------------
__device__ __forceinline__ void t64_core(const float* __restrict__ inb, int inRS,
                                         u16* __restrict__ outb, int outRS2) {
  __shared__ float tile[64][65];
  int tid = threadIdx.x;
  int tx = tid & 15, ty = tid >> 4;
#pragma unroll
  for (int rr = 0; rr < 4; ++rr) {
    int r = ty + rr * 16;
    float4 v = *(const float4*)(inb + (size_t)r * inRS + tx * 4);
    tile[r][tx * 4 + 0] = v.x; tile[r][tx * 4 + 1] = v.y;
    tile[r][tx * 4 + 2] = v.z; tile[r][tx * 4 + 3] = v.w;
  }
  __syncthreads();
  int n = tid >> 2, c8 = tid & 3;
#pragma unroll
  for (int cc = 0; cc < 2; ++cc) {
    int k0 = (c8 + cc * 4) * 8;
    u16x8 o;
#pragma unroll
    for (int j = 0; j < 8; ++j) o[j] = f2bf(tile[k0 + j][n]);
    *(u16x8*)(outb + (size_t)n * outRS2 + k0) = o;
  }
}

// ---------------- single fused weight-transpose kernel (was 4 launches) ----------------
// regions: [0,8192)    t_gu : gate_up_w [E][D][2I] -> gut slab e [2I][D] interleaved
//          [8192,9216) t_sgu: shared gate/up [D][I] -> gut slab 8 interleaved
//          [9216,13312) t_dw: down_w [E][I][D] -> dwt slab e [D][I]
//          [13312,13824) t_sd: shared_down [I][D] -> dwt slab 8
__global__ __launch_bounds__(256)
void t_all_kernel(const float* __restrict__ guw, const float* __restrict__ sgw,
                  const float* __restrict__ suw, const float* __restrict__ dw,
                  const float* __restrict__ sdw, u16* __restrict__ gut,
                  u16* __restrict__ dwt) {
  int b = blockIdx.x;
  if (b < 8192) {
    int z = b >> 9, r = b & 511, kt = r >> 4, nt = r & 15;
    int e = z >> 1, s = z & 1;
    const float* inb = guw + (size_t)e * DDIM * (2 * IDIM) + (size_t)(kt * 64) * (2 * IDIM)
                           + (size_t)s * IDIM + nt * 64;
    u16* outb = gut + (size_t)e * (2 * IDIM) * DDIM + (size_t)(2 * (nt * 64) + s) * DDIM + kt * 64;
    t64_core(inb, 2 * IDIM, outb, 2 * DDIM);
  } else if (b < 9216) {
    int bb = b - 8192;
    int z = bb >> 9, r = bb & 511, kt = r >> 4, nt = r & 15;
    const float* in = z ? suw : sgw;
    const float* inb = in + (size_t)(kt * 64) * IDIM + nt * 64;
    u16* outb = gut + (size_t)NEXP * (2 * IDIM) * DDIM + (size_t)(2 * (nt * 64) + z) * DDIM + kt * 64;
    t64_core(inb, IDIM, outb, 2 * DDIM);
  } else if (b < 13312) {
    int bb = b - 9216;
    int z = bb >> 9, r = bb & 511, kt = r >> 5, nt = r & 31;
    const float* inb = dw + (size_t)z * IDIM * DDIM + (size_t)(kt * 64) * DDIM + nt * 64;
    u16* outb = dwt + (size_t)z * DDIM * IDIM + (size_t)(nt * 64) * IDIM + kt * 64;
    t64_core(inb, DDIM, outb, IDIM);
  } else {
    int bb = b - 13312;
    int kt = bb >> 5, nt = bb & 31;
    const float* inb = sdw + (size_t)(kt * 64) * DDIM + nt * 64;
    u16* outb = dwt + (size_t)NEXP * DDIM * IDIM + (size_t)(nt * 64) * IDIM + kt * 64;
    t64_core(inb, DDIM, outb, IDIM);
  }
}

// ---------------- 256x256 deep-pipelined GEMM (round-2 proven schedule) ----------------
// BM=BN=256, BK=64, 8 waves (2Mx4N), LDS 128KiB dbuf, 4 phases per K-tile.
// Per K-tile: 4 phases, each = {ds_read frag subtile | issue one 16KB stage chunk of
// tile t+1 | setprio(1) + 16 MFMA} separated by raw s_barrier with counted
// s_waitcnt vmcnt(4) (never 0 in the loop).
// Chunk issue order S0=A-mh0, S1=B-nh0, S2=B-nh1, S3=A-mh1 matches consumption order, so
// vmcnt(4) at P0/P1/P2 proves the chunk read this phase has landed for every wave.
// LDS swizzle (T2, both sides): slot s of row r holds global k-chunk s^(r&7); stage
// pre-swizzles the global source (dest stays linear for global_load_lds), reads XOR.
template <bool GATEUP, int KD>
__global__ __launch_bounds__(512)
void gemm8_kernel(const u16* __restrict__ A, const u16* __restrict__ Bt,
                  float* __restrict__ outp, u16* __restrict__ hout,
                  const int* __restrict__ tab, const int* __restrict__ ntl,
                  const int* __restrict__ offs, const int* __restrict__ tlist,
                  const float* __restrict__ pw) {
  constexpr int BK = 64;
  constexpr int NKT = KD / BK;
  // 128 KiB: A dbuf = sm[0..16384), sm[16384..32768); B dbuf = +32768, +49152 (u16 units)
  __shared__ alignas(16) u16 sm[65536];

  int bid = blockIdx.x;
  int bx = bid >> 3;        // M-tile index (slow)
  int by = bid & 7;         // N column (fast; same-col blocks share B slab in L2)
  int nt = *ntl;
  if (bx >= nt) return;
  int tt = tab[bx];
  int e = tt >> 16, rb = tt & 0xffff;
  int seg = offs[e];
  int mcnt = offs[e + 1] - seg;
  int m0 = rb * 256, n0 = by * 256;
  const u16* Bte = Bt + (size_t)e * 2048 * KD + (size_t)n0 * KD;

  int tid = threadIdx.x;
  int lane = tid & 63, w = tid >> 6;
  int wr = w >> 2, wc = w & 3;           // wave grid 2(M) x 4(N), wave owns 128x64 out

  // ---- staging setup ----
  int wq = w & 3;                        // A staging: rows wr*128 + h*64 + wq*16 + [0,16)
  int wch = w >> 1, wo = w & 1;          // B staging: rows wch*64 + wo*16 + s*32 + [0,16)
  int srow = lane >> 3;                  // 0..7 : row within 8-row call
  int swz = (lane & 7) ^ srow;           // pre-swizzled k-chunk to fetch (involution)

  const u16* pA[2][2];                   // [half(mh)][call j]
#pragma unroll
  for (int h = 0; h < 2; ++h)
#pragma unroll
    for (int j = 0; j < 2; ++j) {
      int gl = wr * 128 + h * 64 + wq * 16 + j * 8 + srow;   // local row in tile
      int g = m0 + gl;
      if (g > mcnt - 1) g = mcnt - 1;                        // clamp within segment
      size_t row = GATEUP ? (size_t)tlist[seg + g] : (size_t)(seg + g);
      pA[h][j] = A + row * KD + swz * 8;
    }
  const u16* pB = Bte + (size_t)(wch * 64 + wo * 16 + srow) * KD + swz * 8;

  auto stA = [&](int h, int kn, u16* dst) {
    u16* d = dst + wr * 8192 + wq * 1024 + h * 4096;
    gll16(pA[h][0] + kn, d);
    gll16(pA[h][1] + kn, d + 512);
  };
  auto stB = [&](int s, int kn, u16* dst) {
    u16* d = dst + wch * 4096 + wo * 1024 + s * 2048;
    gll16(pB + (size_t)(s * 32) * KD + kn, d);
    gll16(pB + (size_t)(s * 32 + 8) * KD + kn, d + 512);
  };

  // ---- read-side fragment offsets (u16 units, includes XOR swizzle) ----
  int rlo = lane & 15, g4 = lane >> 4;
  int aoff0 = rlo * 64 + ((g4 ^ (rlo & 7)) * 8);          // ks=0 (k-chunks 0..3)
  int aoff1 = rlo * 64 + (((4 + g4) ^ (rlo & 7)) * 8);    // ks=1 (k-chunks 4..7)

  bf16x8 a0[4][2], a1[4][2], b0[2][2], b1[2][2];
  f32x4 acc[8][4] = {};

  // prologue: tile 0 chunks, issue order S0,S1,S2,S3
  stA(0, 0, sm);
  stB(0, 0, sm + 32768);
  stB(1, 0, sm + 32768);
  stA(1, 0, sm);

  for (int t = 0; t < NKT; ++t) {
    int ab = (t & 1) * 16384;
    const u16* Ar = sm + ab + wr * 8192;
    const u16* Br = sm + 32768 + ab + wc * 4096;
    u16* An = sm + (ab ^ 16384);
    u16* Bn = sm + 32768 + (ab ^ 16384);
    int kn = (t + 1 < NKT) ? (t + 1) * BK : 0;   // clamped restage on last tile (never read)

    // ---- P0: read A-mh0 + B-nh0 | stage S0(t+1) | MFMA Q3(t-1) ----
    asm volatile("s_waitcnt vmcnt(4)" ::: "memory");
    __builtin_amdgcn_s_barrier();
#pragma unroll
    for (int i = 0; i < 4; ++i) {
      a0[i][0] = *(const bf16x8*)(Ar + i * 1024 + aoff0);
      a0[i][1] = *(const bf16x8*)(Ar + i * 1024 + aoff1);
    }
#pragma unroll
    for (int j = 0; j < 2; ++j) {
      b0[j][0] = *(const bf16x8*)(Br + j * 1024 + aoff0);
      b0[j][1] = *(const bf16x8*)(Br + j * 1024 + aoff1);
    }
    stA(0, kn, An);
    if (t) {
      __builtin_amdgcn_s_setprio(1);
#pragma unroll
      for (int i = 0; i < 4; ++i)
#pragma unroll
        for (int j = 0; j < 2; ++j) {
          acc[4 + i][2 + j] = MFMA16(a1[i][0], b1[j][0], acc[4 + i][2 + j]);
          acc[4 + i][2 + j] = MFMA16(a1[i][1], b1[j][1], acc[4 + i][2 + j]);
        }
      __builtin_amdgcn_s_setprio(0);
    }

    // ---- P1: read B-nh1 | stage S1 | MFMA Q0 ----
    asm volatile("s_waitcnt vmcnt(4)" ::: "memory");
    __builtin_amdgcn_s_barrier();
#pragma unroll
    for (int j = 0; j < 2; ++j) {
      b1[j][0] = *(const bf16x8*)(Br + 2048 + j * 1024 + aoff0);
      b1[j][1] = *(const bf16x8*)(Br + 2048 + j * 1024 + aoff1);
    }
    stB(0, kn, Bn);
    __builtin_amdgcn_s_setprio(1);
#pragma unroll
    for (int i = 0; i < 4; ++i)
#pragma unroll
      for (int j = 0; j < 2; ++j) {
        acc[i][j] = MFMA16(a0[i][0], b0[j][0], acc[i][j]);
        acc[i][j] = MFMA16(a0[i][1], b0[j][1], acc[i][j]);
      }
    __builtin_amdgcn_s_setprio(0);

    // ---- P2: read A-mh1 | stage S2 | MFMA Q1 ----
    asm volatile("s_waitcnt vmcnt(4)" ::: "memory");
    __builtin_amdgcn_s_barrier();
#pragma unroll
    for (int i = 0; i < 4; ++i) {
      a1[i][0] = *(const bf16x8*)(Ar + 4096 + i * 1024 + aoff0);
      a1[i][1] = *(const bf16x8*)(Ar + 4096 + i * 1024 + aoff1);
    }
    stB(1, kn, Bn);
    __builtin_amdgcn_s_setprio(1);
#pragma unroll
    for (int i = 0; i < 4; ++i)
#pragma unroll
      for (int j = 0; j < 2; ++j) {
        acc[i][2 + j] = MFMA16(a0[i][0], b1[j][0], acc[i][2 + j]);
        acc[i][2 + j] = MFMA16(a0[i][1], b1[j][1], acc[i][2 + j]);
      }
    __builtin_amdgcn_s_setprio(0);

    // ---- P3: stage S3 | MFMA Q2 (no vmcnt: nothing read this phase) ----
    __builtin_amdgcn_s_barrier();
    stA(1, kn, An);
    __builtin_amdgcn_s_setprio(1);
#pragma unroll
    for (int i = 0; i < 4; ++i)
#pragma unroll
      for (int j = 0; j < 2; ++j) {
        acc[4 + i][j] = MFMA16(a1[i][0], b0[j][0], acc[4 + i][j]);
        acc[4 + i][j] = MFMA16(a1[i][1], b0[j][1], acc[4 + i][j]);
      }
    __builtin_amdgcn_s_setprio(0);
  }
  // final Q3 of last tile
#pragma unroll
  for (int i = 0; i < 4; ++i)
#pragma unroll
    for (int j = 0; j < 2; ++j) {
      acc[4 + i][2 + j] = MFMA16(a1[i][0], b1[j][0], acc[4 + i][2 + j]);
      acc[4 + i][2 + j] = MFMA16(a1[i][1], b1[j][1], acc[4 + i][2 + j]);
    }

  // ---- epilogue: C/D layout col = lane&15 (N), row = (lane>>4)*4 + r (M) ----
  int cn = lane & 15;
  int rq = (lane >> 4) * 4;

  if constexpr (GATEUP) {
#pragma unroll
    for (int mf = 0; mf < 8; ++mf) {
#pragma unroll
      for (int r = 0; r < 4; ++r) {
        int mloc = wr * 128 + mf * 16 + rq + r;
        int mg = m0 + mloc;
        bool valid = (mg < mcnt);
        float p = valid ? pw[seg + mg] : 0.0f;
#pragma unroll
        for (int nf = 0; nf < 4; ++nf) {
          float v = acc[mf][nf][r] * p;       // p applied PRE-silu (matches reference)
          float o = __shfl_xor(v, 1);         // partner column (gate<->up)
          if (!(cn & 1) && valid) {
            float g = v, u2 = o;
            float h = (g / (1.0f + __expf(-g))) * u2;   // silu(g)*u
            int ncol = n0 + wc * 64 + nf * 16 + cn;
            hout[(size_t)(seg + mg) * IDIM + (ncol >> 1)] = f2bf(h);
          }
        }
      }
    }
  } else {
#pragma unroll
    for (int mf = 0; mf < 8; ++mf) {
#pragma unroll
      for (int r = 0; r < 4; ++r) {
        int mloc = wr * 128 + mf * 16 + rq + r;
        int mg = m0 + mloc;
        if (mg < mcnt) {
#pragma unroll
          for (int nf = 0; nf < 4; ++nf) {
            int ncol = n0 + wc * 64 + nf * 16 + cn;
            outp[(size_t)(seg + mg) * DDIM + ncol] = acc[mf][nf][r];
          }
        }
      }
    }
  }
}

// ---------------- final combine: out[t] = dout[p0] + dout[p1] + dout[shared_t] ----------------
__global__ __launch_bounds__(256)
void combine_kernel(const float* __restrict__ dout, const int* __restrict__ pos_of,
                    float* __restrict__ out) {
  int idx = blockIdx.x * 256 + threadIdx.x;
  int t = idx >> 9;              // 512 float4 per row
  int c = (idx & 511) * 4;
  int p0 = pos_of[t * 2];
  int p1 = pos_of[t * 2 + 1];
  float4 a = *(const float4*)(dout + (size_t)p0 * DDIM + c);
  float4 b = *(const float4*)(dout + (size_t)p1 * DDIM + c);
  float4 s = *(const float4*)(dout + (size_t)(NPAIR + t) * DDIM + c);
  float4 o;
  o.x = a.x + b.x + s.x; o.y = a.y + b.y + s.y;
  o.z = a.z + b.z + s.z; o.w = a.w + b.w + s.w;
  *(float4*)(out + (size_t)t * DDIM + c) = o;
}

// ---------------- launch ----------------
extern "C" void kernel_launch(void* const* d_in, const int* in_sizes, int n_in,
                              void* d_out, int out_size, void* d_ws, size_t ws_size,
                              hipStream_t stream) {
  const float* x   = (const float*)d_in[0];
  const float* rw  = (const float*)d_in[1];
  const float* guw = (const float*)d_in[2];
  const float* dw  = (const float*)d_in[3];
  const float* sgw = (const float*)d_in[4];
  const float* suw = (const float*)d_in[5];
  const float* sdw = (const float*)d_in[6];
  float* outp = (float*)d_out;
  (void)in_sizes; (void)n_in; (void)out_size; (void)ws_size;

  char* ws = (char*)d_ws;
  size_t off = 0;
  auto alloc = [&](size_t bytes) -> void* {
    void* p = ws + off;
    off += (bytes + 255) & ~(size_t)255;
    return p;
  };
  // region0: gut (75.5 MB) + xb (16.8 MB) during gateup; overlaid by dout (100.7 MB) for down
  const size_t gut_b  = (size_t)(NEXP + 1) * 2 * IDIM * DDIM * 2;   // 75.5 MB
  const size_t xb_b   = (size_t)T_TOK * DDIM * 2;                   // 16.8 MB
  const size_t dout_b = (size_t)TPAIR * DDIM * 4;                   // 100.7 MB
  char* region0 = (char*)alloc(dout_b > gut_b + xb_b ? dout_b : gut_b + xb_b);
  u16*   gut  = (u16*)region0;
  u16*   xb   = (u16*)(region0 + gut_b);
  float* dout = (float*)region0;

  u16* dwt = (u16*)alloc((size_t)(NEXP + 1) * DDIM * IDIM * 2);     // 37.75 MB
  u16* he  = (u16*)alloc((size_t)TPAIR * IDIM * 2);                 // 25.2 MB
  int* top_idx = (int*)alloc(T_TOK * 2 * 4);
  float* top_w = (float*)alloc(T_TOK * 2 * 4);
  int* counts  = (int*)alloc(NEXP * 4);
  int* offs    = (int*)alloc((NEXP + 2) * 4);
  int* fill    = (int*)alloc(NEXP * 4);
  int* tab     = (int*)alloc(144 * 4);
  int* ntl     = (int*)alloc(4);
  int* tlist   = (int*)alloc(TPAIR * 4);
  float* pw    = (float*)alloc(TPAIR * 4);
  int* pos_of  = (int*)alloc(NPAIR * 4);

  // routing (+ fused fp32->bf16 conversion of x)
  init_kernel<<<dim3(1), dim3(64), 0, stream>>>(counts);
  router_kernel<<<dim3(T_TOK), dim3(256), 0, stream>>>(x, rw, top_idx, top_w, counts, xb);
  offsets_kernel<<<dim3(1), dim3(1), 0, stream>>>(counts, offs, fill, tab, ntl);
  scatter_kernel<<<dim3(16), dim3(256), 0, stream>>>(top_idx, top_w, offs, fill, tlist, pw, pos_of);

  // fused weight transpose pre-pass (single launch, was 4)
  t_all_kernel<<<dim3(13824), dim3(256), 0, stream>>>(guw, sgw, suw, dw, sdw, gut, dwt);

  // gateup over all 12288 pairs (routed + shared): he = silu(p*(x@Wg)) * (p*(x@Wu))
  gemm8_kernel<true, DDIM><<<dim3(56 * 8), dim3(512), 0, stream>>>(
      xb, gut, nullptr, he, tab, ntl, offs, tlist, pw);
  // down over all pairs: dout[pair] = he[pair] @ Wd   (overlays gut/xb — both dead now)
  gemm8_kernel<false, IDIM><<<dim3(56 * 8), dim3(512), 0, stream>>>(
      he, dwt, dout, nullptr, tab, ntl, offs, tlist, pw);

  // out[t] = dout[p0] + dout[p1] + dout[8192+t]
  combine_kernel<<<dim3(8192), dim3(256), 0, stream>>>(dout, pos_of, outp);
}

// Round 9
// 652.751 us; speedup vs baseline: 1.0887x; 1.0037x over previous
//
#include <hip/hip_runtime.h>
#include <hip/hip_bf16.h>

// Problem constants
#define T_TOK 4096
#define DDIM  2048
#define IDIM  1024
#define NEXP  8
#define NPAIR 8192    // T_TOK * top_k
#define TPAIR 12288   // NPAIR + T_TOK shared rows

typedef unsigned short u16;
typedef __bf16 bf16x8 __attribute__((ext_vector_type(8)));
typedef float  f32x4  __attribute__((ext_vector_type(4)));
typedef unsigned short u16x4 __attribute__((ext_vector_type(4)));
typedef unsigned short u16x8 __attribute__((ext_vector_type(8)));

__device__ __forceinline__ u16 f2bf(float f) {
  union { float f; unsigned u; } v; v.f = f;
  unsigned r = v.u + 0x7fffu + ((v.u >> 16) & 1u);   // RNE
  return (u16)(r >> 16);
}

// async global->LDS, 16B per lane; LDS dest is wave-uniform base (+lane*16 by HW)
__device__ __forceinline__ void gll16(const void* g, void* l) {
  __builtin_amdgcn_global_load_lds(
      (__attribute__((address_space(1))) void*)(g),
      (__attribute__((address_space(3))) void*)(l),
      16, 0, 0);
}

#define MFMA16(a, b, c) __builtin_amdgcn_mfma_f32_16x16x32_bf16((a), (b), (c), 0, 0, 0)

// ---------------- router: logits = x @ rw (fp64 accum), top-2, sigmoid ----------------
// Fused: also emits the bf16 copy of x (kills the separate cvt_x kernel + launch bubble).
__global__ __launch_bounds__(256)
void router_kernel(const float* __restrict__ x, const float* __restrict__ rw,
                   int* __restrict__ top_idx, float* __restrict__ top_w,
                   int* __restrict__ counts, u16* __restrict__ xb) {
  int t = blockIdx.x;
  int tid = threadIdx.x;
  int lane = tid & 63, wave = tid >> 6;
  const float* xr = x + (size_t)t * DDIM;

  // bf16 conversion of this token's row (coalesced, 8 elems/thread)
  {
    int d0 = tid * 8;
    float4 v0 = *(const float4*)(xr + d0);
    float4 v1 = *(const float4*)(xr + d0 + 4);
    u16x8 o;
    o[0] = f2bf(v0.x); o[1] = f2bf(v0.y); o[2] = f2bf(v0.z); o[3] = f2bf(v0.w);
    o[4] = f2bf(v1.x); o[5] = f2bf(v1.y); o[6] = f2bf(v1.z); o[7] = f2bf(v1.w);
    *(u16x8*)(xb + (size_t)t * DDIM + d0) = o;
  }

  double acc[NEXP];
#pragma unroll
  for (int e = 0; e < NEXP; ++e) acc[e] = 0.0;
  for (int d = tid; d < DDIM; d += 256) {
    double xv = (double)xr[d];
    const float* r = rw + (size_t)d * NEXP;
#pragma unroll
    for (int e = 0; e < NEXP; ++e) acc[e] += xv * (double)r[e];
  }
  __shared__ double wred[4][NEXP];
#pragma unroll
  for (int e = 0; e < NEXP; ++e) {
    double v = acc[e];
    for (int s = 32; s > 0; s >>= 1) v += __shfl_down(v, s);
    if (lane == 0) wred[wave][e] = v;
  }
  __syncthreads();
  if (tid == 0) {
    float lg[NEXP];
#pragma unroll
    for (int e = 0; e < NEXP; ++e)
      lg[e] = (float)(wred[0][e] + wred[1][e] + wred[2][e] + wred[3][e]);
    int e0 = 0; float v0 = lg[0];
    for (int e = 1; e < NEXP; ++e) if (lg[e] > v0) { v0 = lg[e]; e0 = e; }
    int e1 = -1; float v1 = -3.4e38f;
    for (int e = 0; e < NEXP; ++e) if (e != e0 && lg[e] > v1) { v1 = lg[e]; e1 = e; }
    float p0 = 1.0f / (1.0f + __expf(-v0));
    float p1 = 1.0f / (1.0f + __expf(-v1));
    top_idx[t * 2 + 0] = e0; top_idx[t * 2 + 1] = e1;
    top_w[t * 2 + 0] = p0;  top_w[t * 2 + 1] = p1;
    atomicAdd(&counts[e0], 1);
    atomicAdd(&counts[e1], 1);
  }
}

__global__ void init_kernel(int* counts) {
  if (threadIdx.x < NEXP) counts[threadIdx.x] = 0;
}

// prefix sum over 8 routed experts + shared (e=8); 256-row tile table
__global__ void offsets_kernel(const int* __restrict__ counts, int* __restrict__ offs,
                               int* __restrict__ fill, int* __restrict__ tab,
                               int* __restrict__ ntl) {
  if (blockIdx.x == 0 && threadIdx.x == 0) {
    int off = 0, nt = 0;
    for (int e = 0; e < NEXP; ++e) {
      offs[e] = off;
      int c = counts[e];
      int tb = (c + 255) >> 8;
      for (int t = 0; t < tb; ++t) tab[nt++] = (e << 16) | t;
      off += c;
      fill[e] = 0;
    }
    offs[NEXP] = NPAIR;       // routed total is exactly NPAIR
    offs[NEXP + 1] = TPAIR;   // shared region
    for (int t = 0; t < 16; ++t) tab[nt++] = (NEXP << 16) | t;  // 4096/256 shared tiles
    *ntl = nt;
    for (int i = nt; i < 144; ++i) tab[i] = 0;
  }
}

__global__ __launch_bounds__(256)
void scatter_kernel(const int* __restrict__ top_idx, const float* __restrict__ top_w,
                    const int* __restrict__ offs, int* __restrict__ fill,
                    int* __restrict__ tlist, float* __restrict__ pw,
                    int* __restrict__ pos_of) {
  int t = blockIdx.x * blockDim.x + threadIdx.x;
  if (t >= T_TOK) return;
#pragma unroll
  for (int k = 0; k < 2; ++k) {
    int e = top_idx[t * 2 + k];
    float w = top_w[t * 2 + k];
    int pos = offs[e] + atomicAdd(&fill[e], 1);
    tlist[pos] = t;
    pw[pos] = w;
    pos_of[t * 2 + k] = pos;
  }
  tlist[NPAIR + t] = t;   // shared region: identity gather, weight 1
  pw[NPAIR + t] = 1.0f;
}

// ---------------- 64x64 fp32->bf16 transpose core ----------------
// write side: 8 lanes cover one output row -> 128B contiguous stores per row
__device__ __forceinline__ void t64_core(const float* __restrict__ inb, int inRS,
                                         u16* __restrict__ outb, int outRS2) {
  __shared__ float tile[64][65];
  int tid = threadIdx.x;
  int tx = tid & 15, ty = tid >> 4;
#pragma unroll
  for (int rr = 0; rr < 4; ++rr) {
    int r = ty + rr * 16;
    float4 v = *(const float4*)(inb + (size_t)r * inRS + tx * 4);
    tile[r][tx * 4 + 0] = v.x; tile[r][tx * 4 + 1] = v.y;
    tile[r][tx * 4 + 2] = v.z; tile[r][tx * 4 + 3] = v.w;
  }
  __syncthreads();
  int n2 = tid >> 3, c8 = tid & 7;   // n2: out row group, c8: 16B col chunk
  int k0 = c8 * 8;
#pragma unroll
  for (int half = 0; half < 2; ++half) {
    int n = n2 + half * 32;
    u16x8 o;
#pragma unroll
    for (int j = 0; j < 8; ++j) o[j] = f2bf(tile[k0 + j][n]);
    *(u16x8*)(outb + (size_t)n * outRS2 + k0) = o;
  }
}

// ---------------- single fused weight-transpose kernel ----------------
// regions: [0,8192)    t_gu : gate_up_w [E][D][2I] -> gut slab e [2I][D] interleaved
//          [8192,9216) t_sgu: shared gate/up [D][I] -> gut slab 8 interleaved
//          [9216,13312) t_dw: down_w [E][I][D] -> dwt slab e [D][I]
//          [13312,13824) t_sd: shared_down [I][D] -> dwt slab 8
__global__ __launch_bounds__(256)
void t_all_kernel(const float* __restrict__ guw, const float* __restrict__ sgw,
                  const float* __restrict__ suw, const float* __restrict__ dw,
                  const float* __restrict__ sdw, u16* __restrict__ gut,
                  u16* __restrict__ dwt) {
  int b = blockIdx.x;
  if (b < 8192) {
    int z = b >> 9, r = b & 511, kt = r >> 4, nt = r & 15;
    int e = z >> 1, s = z & 1;
    const float* inb = guw + (size_t)e * DDIM * (2 * IDIM) + (size_t)(kt * 64) * (2 * IDIM)
                           + (size_t)s * IDIM + nt * 64;
    u16* outb = gut + (size_t)e * (2 * IDIM) * DDIM + (size_t)(2 * (nt * 64) + s) * DDIM + kt * 64;
    t64_core(inb, 2 * IDIM, outb, 2 * DDIM);
  } else if (b < 9216) {
    int bb = b - 8192;
    int z = bb >> 9, r = bb & 511, kt = r >> 4, nt = r & 15;
    const float* in = z ? suw : sgw;
    const float* inb = in + (size_t)(kt * 64) * IDIM + nt * 64;
    u16* outb = gut + (size_t)NEXP * (2 * IDIM) * DDIM + (size_t)(2 * (nt * 64) + z) * DDIM + kt * 64;
    t64_core(inb, IDIM, outb, 2 * DDIM);
  } else if (b < 13312) {
    int bb = b - 9216;
    int z = bb >> 9, r = bb & 511, kt = r >> 5, nt = r & 31;
    const float* inb = dw + (size_t)z * IDIM * DDIM + (size_t)(kt * 64) * DDIM + nt * 64;
    u16* outb = dwt + (size_t)z * DDIM * IDIM + (size_t)(nt * 64) * IDIM + kt * 64;
    t64_core(inb, DDIM, outb, IDIM);
  } else {
    int bb = b - 13312;
    int kt = bb >> 5, nt = bb & 31;
    const float* inb = sdw + (size_t)(kt * 64) * DDIM + nt * 64;
    u16* outb = dwt + (size_t)NEXP * DDIM * IDIM + (size_t)(nt * 64) * IDIM + kt * 64;
    t64_core(inb, DDIM, outb, IDIM);
  }
}

// ---------------- 256x256 deep-pipelined GEMM (round-2 proven schedule + XCD swizzle) ----------------
// BM=BN=256, BK=64, 8 waves (2Mx4N), LDS 128KiB dbuf, 4 phases per K-tile.
// XCD swizzle (T1): grid is exactly 448 = 8 XCDs x 56. Hardware dispatches consecutive
// blockIdx round-robin across XCDs; remap so XCD k gets logical tiles [k*56,(k+1)*56) =
// 7 consecutive bx tile-rows x all 8 by columns -> the 8 blocks sharing one (gathered)
// A-tile are co-resident on ONE XCD's L2, and B sub-slabs get cross-bx reuse.
template <bool GATEUP, int KD>
__global__ __launch_bounds__(512)
void gemm8_kernel(const u16* __restrict__ A, const u16* __restrict__ Bt,
                  float* __restrict__ outp, u16* __restrict__ hout,
                  const int* __restrict__ tab, const int* __restrict__ ntl,
                  const int* __restrict__ offs, const int* __restrict__ tlist,
                  const float* __restrict__ pw) {
  constexpr int BK = 64;
  constexpr int NKT = KD / BK;
  // 128 KiB: A dbuf = sm[0..16384), sm[16384..32768); B dbuf = +32768, +49152 (u16 units)
  __shared__ alignas(16) u16 sm[65536];

  int bid0 = blockIdx.x;
  int bid = (bid0 & 7) * 56 + (bid0 >> 3);   // bijective XCD swizzle (448 = 8*56)
  int bx = bid >> 3;        // M-tile index (slow)
  int by = bid & 7;         // N column (fast)
  int nt = *ntl;
  if (bx >= nt) return;
  int tt = tab[bx];
  int e = tt >> 16, rb = tt & 0xffff;
  int seg = offs[e];
  int mcnt = offs[e + 1] - seg;
  int m0 = rb * 256, n0 = by * 256;
  const u16* Bte = Bt + (size_t)e * 2048 * KD + (size_t)n0 * KD;

  int tid = threadIdx.x;
  int lane = tid & 63, w = tid >> 6;
  int wr = w >> 2, wc = w & 3;           // wave grid 2(M) x 4(N), wave owns 128x64 out

  // ---- staging setup ----
  int wq = w & 3;                        // A staging: rows wr*128 + h*64 + wq*16 + [0,16)
  int wch = w >> 1, wo = w & 1;          // B staging: rows wch*64 + wo*16 + s*32 + [0,16)
  int srow = lane >> 3;                  // 0..7 : row within 8-row call
  int swz = (lane & 7) ^ srow;           // pre-swizzled k-chunk to fetch (involution)

  const u16* pA[2][2];                   // [half(mh)][call j]
#pragma unroll
  for (int h = 0; h < 2; ++h)
#pragma unroll
    for (int j = 0; j < 2; ++j) {
      int gl = wr * 128 + h * 64 + wq * 16 + j * 8 + srow;   // local row in tile
      int g = m0 + gl;
      if (g > mcnt - 1) g = mcnt - 1;                        // clamp within segment
      size_t row = GATEUP ? (size_t)tlist[seg + g] : (size_t)(seg + g);
      pA[h][j] = A + row * KD + swz * 8;
    }
  const u16* pB = Bte + (size_t)(wch * 64 + wo * 16 + srow) * KD + swz * 8;

  auto stA = [&](int h, int kn, u16* dst) {
    u16* d = dst + wr * 8192 + wq * 1024 + h * 4096;
    gll16(pA[h][0] + kn, d);
    gll16(pA[h][1] + kn, d + 512);
  };
  auto stB = [&](int s, int kn, u16* dst) {
    u16* d = dst + wch * 4096 + wo * 1024 + s * 2048;
    gll16(pB + (size_t)(s * 32) * KD + kn, d);
    gll16(pB + (size_t)(s * 32 + 8) * KD + kn, d + 512);
  };

  // ---- read-side fragment offsets (u16 units, includes XOR swizzle) ----
  int rlo = lane & 15, g4 = lane >> 4;
  int aoff0 = rlo * 64 + ((g4 ^ (rlo & 7)) * 8);          // ks=0 (k-chunks 0..3)
  int aoff1 = rlo * 64 + (((4 + g4) ^ (rlo & 7)) * 8);    // ks=1 (k-chunks 4..7)

  bf16x8 a0[4][2], a1[4][2], b0[2][2], b1[2][2];
  f32x4 acc[8][4] = {};

  // prologue: tile 0 chunks, issue order S0,S1,S2,S3
  stA(0, 0, sm);
  stB(0, 0, sm + 32768);
  stB(1, 0, sm + 32768);
  stA(1, 0, sm);

  for (int t = 0; t < NKT; ++t) {
    int ab = (t & 1) * 16384;
    const u16* Ar = sm + ab + wr * 8192;
    const u16* Br = sm + 32768 + ab + wc * 4096;
    u16* An = sm + (ab ^ 16384);
    u16* Bn = sm + 32768 + (ab ^ 16384);
    int kn = (t + 1 < NKT) ? (t + 1) * BK : 0;   // clamped restage on last tile (never read)

    // ---- P0: read A-mh0 + B-nh0 | stage S0(t+1) | MFMA Q3(t-1) ----
    asm volatile("s_waitcnt vmcnt(4)" ::: "memory");
    __builtin_amdgcn_s_barrier();
#pragma unroll
    for (int i = 0; i < 4; ++i) {
      a0[i][0] = *(const bf16x8*)(Ar + i * 1024 + aoff0);
      a0[i][1] = *(const bf16x8*)(Ar + i * 1024 + aoff1);
    }
#pragma unroll
    for (int j = 0; j < 2; ++j) {
      b0[j][0] = *(const bf16x8*)(Br + j * 1024 + aoff0);
      b0[j][1] = *(const bf16x8*)(Br + j * 1024 + aoff1);
    }
    stA(0, kn, An);
    if (t) {
      __builtin_amdgcn_s_setprio(1);
#pragma unroll
      for (int i = 0; i < 4; ++i)
#pragma unroll
        for (int j = 0; j < 2; ++j) {
          acc[4 + i][2 + j] = MFMA16(a1[i][0], b1[j][0], acc[4 + i][2 + j]);
          acc[4 + i][2 + j] = MFMA16(a1[i][1], b1[j][1], acc[4 + i][2 + j]);
        }
      __builtin_amdgcn_s_setprio(0);
    }

    // ---- P1: read B-nh1 | stage S1 | MFMA Q0 ----
    asm volatile("s_waitcnt vmcnt(4)" ::: "memory");
    __builtin_amdgcn_s_barrier();
#pragma unroll
    for (int j = 0; j < 2; ++j) {
      b1[j][0] = *(const bf16x8*)(Br + 2048 + j * 1024 + aoff0);
      b1[j][1] = *(const bf16x8*)(Br + 2048 + j * 1024 + aoff1);
    }
    stB(0, kn, Bn);
    __builtin_amdgcn_s_setprio(1);
#pragma unroll
    for (int i = 0; i < 4; ++i)
#pragma unroll
      for (int j = 0; j < 2; ++j) {
        acc[i][j] = MFMA16(a0[i][0], b0[j][0], acc[i][j]);
        acc[i][j] = MFMA16(a0[i][1], b0[j][1], acc[i][j]);
      }
    __builtin_amdgcn_s_setprio(0);

    // ---- P2: read A-mh1 | stage S2 | MFMA Q1 ----
    asm volatile("s_waitcnt vmcnt(4)" ::: "memory");
    __builtin_amdgcn_s_barrier();
#pragma unroll
    for (int i = 0; i < 4; ++i) {
      a1[i][0] = *(const bf16x8*)(Ar + 4096 + i * 1024 + aoff0);
      a1[i][1] = *(const bf16x8*)(Ar + 4096 + i * 1024 + aoff1);
    }
    stB(1, kn, Bn);
    __builtin_amdgcn_s_setprio(1);
#pragma unroll
    for (int i = 0; i < 4; ++i)
#pragma unroll
      for (int j = 0; j < 2; ++j) {
        acc[i][2 + j] = MFMA16(a0[i][0], b1[j][0], acc[i][2 + j]);
        acc[i][2 + j] = MFMA16(a0[i][1], b1[j][1], acc[i][2 + j]);
      }
    __builtin_amdgcn_s_setprio(0);

    // ---- P3: stage S3 | MFMA Q2 (no vmcnt: nothing read this phase) ----
    __builtin_amdgcn_s_barrier();
    stA(1, kn, An);
    __builtin_amdgcn_s_setprio(1);
#pragma unroll
    for (int i = 0; i < 4; ++i)
#pragma unroll
      for (int j = 0; j < 2; ++j) {
        acc[4 + i][j] = MFMA16(a1[i][0], b0[j][0], acc[4 + i][j]);
        acc[4 + i][j] = MFMA16(a1[i][1], b0[j][1], acc[4 + i][j]);
      }
    __builtin_amdgcn_s_setprio(0);
  }
  // final Q3 of last tile
#pragma unroll
  for (int i = 0; i < 4; ++i)
#pragma unroll
    for (int j = 0; j < 2; ++j) {
      acc[4 + i][2 + j] = MFMA16(a1[i][0], b1[j][0], acc[4 + i][2 + j]);
      acc[4 + i][2 + j] = MFMA16(a1[i][1], b1[j][1], acc[4 + i][2 + j]);
    }

  // ---- epilogue: C/D layout col = lane&15 (N), row = (lane>>4)*4 + r (M) ----
  int cn = lane & 15;
  int rq = (lane >> 4) * 4;

  if constexpr (GATEUP) {
#pragma unroll
    for (int mf = 0; mf < 8; ++mf) {
#pragma unroll
      for (int r = 0; r < 4; ++r) {
        int mloc = wr * 128 + mf * 16 + rq + r;
        int mg = m0 + mloc;
        bool valid = (mg < mcnt);
        float p = valid ? pw[seg + mg] : 0.0f;
#pragma unroll
        for (int nf = 0; nf < 4; ++nf) {
          float v = acc[mf][nf][r] * p;       // p applied PRE-silu (matches reference)
          float o = __shfl_xor(v, 1);         // partner column (gate<->up)
          if (!(cn & 1) && valid) {
            float g = v, u2 = o;
            float h = (g / (1.0f + __expf(-g))) * u2;   // silu(g)*u
            int ncol = n0 + wc * 64 + nf * 16 + cn;
            hout[(size_t)(seg + mg) * IDIM + (ncol >> 1)] = f2bf(h);
          }
        }
      }
    }
  } else {
#pragma unroll
    for (int mf = 0; mf < 8; ++mf) {
#pragma unroll
      for (int r = 0; r < 4; ++r) {
        int mloc = wr * 128 + mf * 16 + rq + r;
        int mg = m0 + mloc;
        if (mg < mcnt) {
#pragma unroll
          for (int nf = 0; nf < 4; ++nf) {
            int ncol = n0 + wc * 64 + nf * 16 + cn;
            outp[(size_t)(seg + mg) * DDIM + ncol] = acc[mf][nf][r];
          }
        }
      }
    }
  }
}

// ---------------- final combine: out[t] = dout[p0] + dout[p1] + dout[shared_t] ----------------
__global__ __launch_bounds__(256)
void combine_kernel(const float* __restrict__ dout, const int* __restrict__ pos_of,
                    float* __restrict__ out) {
  int idx = blockIdx.x * 256 + threadIdx.x;
  int t = idx >> 9;              // 512 float4 per row
  int c = (idx & 511) * 4;
  int p0 = pos_of[t * 2];
  int p1 = pos_of[t * 2 + 1];
  float4 a = *(const float4*)(dout + (size_t)p0 * DDIM + c);
  float4 b = *(const float4*)(dout + (size_t)p1 * DDIM + c);
  float4 s = *(const float4*)(dout + (size_t)(NPAIR + t) * DDIM + c);
  float4 o;
  o.x = a.x + b.x + s.x; o.y = a.y + b.y + s.y;
  o.z = a.z + b.z + s.z; o.w = a.w + b.w + s.w;
  *(float4*)(out + (size_t)t * DDIM + c) = o;
}

// ---------------- launch ----------------
extern "C" void kernel_launch(void* const* d_in, const int* in_sizes, int n_in,
                              void* d_out, int out_size, void* d_ws, size_t ws_size,
                              hipStream_t stream) {
  const float* x   = (const float*)d_in[0];
  const float* rw  = (const float*)d_in[1];
  const float* guw = (const float*)d_in[2];
  const float* dw  = (const float*)d_in[3];
  const float* sgw = (const float*)d_in[4];
  const float* suw = (const float*)d_in[5];
  const float* sdw = (const float*)d_in[6];
  float* outp = (float*)d_out;
  (void)in_sizes; (void)n_in; (void)out_size; (void)ws_size;

  char* ws = (char*)d_ws;
  size_t off = 0;
  auto alloc = [&](size_t bytes) -> void* {
    void* p = ws + off;
    off += (bytes + 255) & ~(size_t)255;
    return p;
  };
  // region0: gut (75.5 MB) + xb (16.8 MB) during gateup; overlaid by dout (100.7 MB) for down
  const size_t gut_b  = (size_t)(NEXP + 1) * 2 * IDIM * DDIM * 2;   // 75.5 MB
  const size_t xb_b   = (size_t)T_TOK * DDIM * 2;                   // 16.8 MB
  const size_t dout_b = (size_t)TPAIR * DDIM * 4;                   // 100.7 MB
  char* region0 = (char*)alloc(dout_b > gut_b + xb_b ? dout_b : gut_b + xb_b);
  u16*   gut  = (u16*)region0;
  u16*   xb   = (u16*)(region0 + gut_b);
  float* dout = (float*)region0;

  u16* dwt = (u16*)alloc((size_t)(NEXP + 1) * DDIM * IDIM * 2);     // 37.75 MB
  u16* he  = (u16*)alloc((size_t)TPAIR * IDIM * 2);                 // 25.2 MB
  int* top_idx = (int*)alloc(T_TOK * 2 * 4);
  float* top_w = (float*)alloc(T_TOK * 2 * 4);
  int* counts  = (int*)alloc(NEXP * 4);
  int* offs    = (int*)alloc((NEXP + 2) * 4);
  int* fill    = (int*)alloc(NEXP * 4);
  int* tab     = (int*)alloc(144 * 4);
  int* ntl     = (int*)alloc(4);
  int* tlist   = (int*)alloc(TPAIR * 4);
  float* pw    = (float*)alloc(TPAIR * 4);
  int* pos_of  = (int*)alloc(NPAIR * 4);

  // routing (+ fused fp32->bf16 conversion of x)
  init_kernel<<<dim3(1), dim3(64), 0, stream>>>(counts);
  router_kernel<<<dim3(T_TOK), dim3(256), 0, stream>>>(x, rw, top_idx, top_w, counts, xb);
  offsets_kernel<<<dim3(1), dim3(1), 0, stream>>>(counts, offs, fill, tab, ntl);
  scatter_kernel<<<dim3(16), dim3(256), 0, stream>>>(top_idx, top_w, offs, fill, tlist, pw, pos_of);

  // fused weight transpose pre-pass (single launch)
  t_all_kernel<<<dim3(13824), dim3(256), 0, stream>>>(guw, sgw, suw, dw, sdw, gut, dwt);

  // gateup over all 12288 pairs (routed + shared): he = silu(p*(x@Wg)) * (p*(x@Wu))
  gemm8_kernel<true, DDIM><<<dim3(56 * 8), dim3(512), 0, stream>>>(
      xb, gut, nullptr, he, tab, ntl, offs, tlist, pw);
  // down over all pairs: dout[pair] = he[pair] @ Wd   (overlays gut/xb — both dead now)
  gemm8_kernel<false, IDIM><<<dim3(56 * 8), dim3(512), 0, stream>>>(
      he, dwt, dout, nullptr, tab, ntl, offs, tlist, pw);

  // out[t] = dout[p0] + dout[p1] + dout[8192+t]
  combine_kernel<<<dim3(8192), dim3(256), 0, stream>>>(dout, pos_of, outp);
}